// Round 10
// baseline (139.425 us; speedup 1.0000x reference)
//
#include <hip/hip_runtime.h>
#include <hip/hip_bf16.h>
#include <math.h>

// HMM forward (logZ), K=64 tags, V=50000, D=128, BATCH=8192, L=126.
// Transposed MFMA recurrence: beta_next = (T'^T x beta) .* e, with the MFMA
// C-layout -> next-step B-layout transform done by pure in-lane register
// renaming (tag relabeling absorbed into the T'^T A-operand).
// r10: emission gather is PHASE-STAGED into LDS via global_load_lds
// (14 steps/phase, double-buffered, one vmcnt(0) per phase) — r8/r9 showed
// the per-step vmcnt-domain gather ring serialized at ~850 cyc/step.
//
// ws layout:
//   [0, 6,400,000)        btn_bf[v][k]  bf16  raw exp(logit)
//   [6,400,000, +16384)   A[i][j]       f32   softmax(WA, col BOS=-inf)+EPS
//   [6,416,384, +256)     sumexp[k]     f32
//   [6,416,640, +200704)  partial[k][784] f32 per-block column sums

#define KT 64
#define VV 50000
#define DD 128
#define BOS_T 62
#define EOS_T 63
#define LLEN 126
#define EPSF 1e-45f
#define SCALE_F 65536.0f
#define LOG_TOTAL_SCALE (2016.0f * 0.6931471805599453f)
#define NBLK 782          // k_emit grid
#define PBLK 784          // padded partial row
#define TPH 14            // k_fwd steps per phase (126 = 9*14)
#define NPH 9

#define BTN_OFF   0
#define A_OFF     6400000
#define SUM_OFF   6416384
#define PART_OFF  6416640

typedef short short8 __attribute__((ext_vector_type(8)));
typedef float f32x4  __attribute__((ext_vector_type(4)));

union U8 { short8 v; unsigned u[4]; short s[8]; };

static __device__ inline unsigned short f2bf_u(float x) {
    __hip_bfloat16 h = __float2bfloat16(x);
    return *reinterpret_cast<unsigned short*>(&h);
}
static __device__ inline short f2bf(float x) { return (short)f2bf_u(x); }

#if __has_builtin(__builtin_amdgcn_cvt_pk_bf16_f32)
typedef __bf16 bf16x2 __attribute__((ext_vector_type(2)));
static __device__ inline unsigned pk2(float a, float b) {
    bf16x2 r = __builtin_amdgcn_cvt_pk_bf16_f32(a, b);
    return *reinterpret_cast<unsigned*>(&r);
}
#else
static __device__ inline unsigned pk2(float a, float b) {
    union { float f; unsigned u; } ua, ub;
    ua.f = a; ub.f = b;
    return ((ua.u + 0x8000u) >> 16) | ((ub.u + 0x8000u) & 0xFFFF0000u);
}
#endif
static __device__ inline float lo16(unsigned u) { union { unsigned i; float f; } c; c.i = u << 16;        return c.f; }
static __device__ inline float hi16(unsigned u) { union { unsigned i; float f; } c; c.i = u & 0xffff0000u; return c.f; }

// async global(per-lane addr) -> LDS(uniform base + lane*16B), 16 B/lane
#if __has_builtin(__builtin_amdgcn_global_load_lds)
#define GLLDS(gp, lbase)                                                        \
    __builtin_amdgcn_global_load_lds(                                           \
        (__attribute__((address_space(1))) void*)const_cast<unsigned short*>(gp),\
        (__attribute__((address_space(3))) void*)(lbase), 16, 0, 0)
#else
#define GLLDS(gp, lbase)                                                        \
    do { *(uint4*)((unsigned short*)(lbase) + (threadIdx.x & 63) * 8) =         \
             *(const uint4*)(gp); } while (0)
#endif

// ---------------------------------------------------------------- btn_bf[v][k] = bf16(exp(ThetaB[k].E[v]))  (MFMA GEMM)
// Operand-swapped (A=ThetaB rows=tags, B=E^T cols=v): C rows are tags, so
// each lane's 4 C-regs are 4 CONSECUTIVE tags of one v-row -> 8B uint2 stores
// (r9 had 16 scattered 2B stores per lane).
__global__ __launch_bounds__(256) void k_emit(const float* __restrict__ ThetaB,
                                              const float* __restrict__ E,
                                              unsigned short* __restrict__ btn_bf,
                                              float* __restrict__ partial) {
    __shared__ float red[4][KT];
    int t    = threadIdx.x;
    int lane = t & 63;
    int w    = t >> 6;
    int n    = lane & 15;
    int q    = lane >> 4;
    int v0   = (blockIdx.x * 4 + w) * 16;

    // B-frags from E rows (cold HBM traffic — issue early): B[k=q*8+j][n=v]
    int rowE = v0 + n;
    bool valid = rowE < VV;
    rowE = valid ? rowE : VV - 1;
    float4 ex[4][2];
#pragma unroll
    for (int kt = 0; kt < 4; ++kt) {
        const float* p = E + (size_t)rowE * DD + kt * 32 + q * 8;
        ex[kt][0] = *(const float4*)p;
        ex[kt][1] = *(const float4*)(p + 4);
    }

    // A-frags from ThetaB: A[m=tag][k]: lane m=lane&15, k=q*8+j
    short8 Th[4][4];
#pragma unroll
    for (int kt = 0; kt < 4; ++kt)
#pragma unroll
        for (int mt = 0; mt < 4; ++mt) {
            const float* p = ThetaB + (mt * 16 + n) * DD + kt * 32 + q * 8;
            float4 x = *(const float4*)p;
            float4 y = *(const float4*)(p + 4);
            U8 f;
            f.u[0] = pk2(x.x, x.y); f.u[1] = pk2(x.z, x.w);
            f.u[2] = pk2(y.x, y.y); f.u[3] = pk2(y.z, y.w);
            Th[kt][mt] = f.v;
        }

    short8 Ef[4];
#pragma unroll
    for (int kt = 0; kt < 4; ++kt) {
        U8 f;
        f.u[0] = pk2(ex[kt][0].x, ex[kt][0].y); f.u[1] = pk2(ex[kt][0].z, ex[kt][0].w);
        f.u[2] = pk2(ex[kt][1].x, ex[kt][1].y); f.u[3] = pk2(ex[kt][1].z, ex[kt][1].w);
        Ef[kt] = f.v;
    }

#pragma unroll
    for (int mt = 0; mt < 4; ++mt) {
        f32x4 C = {0.f, 0.f, 0.f, 0.f};
#pragma unroll
        for (int kt = 0; kt < 4; ++kt)
            C = __builtin_amdgcn_mfma_f32_16x16x32_bf16(Th[kt][mt], Ef[kt], C, 0, 0, 0);
        // C[r]: tag = mt*16 + q*4 + r, v-col = n
        float e[4];
#pragma unroll
        for (int r = 0; r < 4; ++r) e[r] = __expf(C[r]);
        if (valid) {
            uint2 st = make_uint2(pk2(e[0], e[1]), pk2(e[2], e[3]));
            *(uint2*)(btn_bf + (size_t)rowE * KT + mt * 16 + q * 4) = st;
        }
        // column sums: reduce over the 16 v-lanes (lane bits 0-3)
#pragma unroll
        for (int r = 0; r < 4; ++r) {
            float s = valid ? e[r] : 0.0f;
            s += __shfl_xor(s, 1, 64);
            s += __shfl_xor(s, 2, 64);
            s += __shfl_xor(s, 4, 64);
            s += __shfl_xor(s, 8, 64);
            if (n == 0) red[w][mt * 16 + q * 4 + r] = s;
        }
    }
    __syncthreads();
    if (w == 0) {
        float s = red[0][lane] + red[1][lane] + red[2][lane] + red[3][lane];
        partial[lane * PBLK + blockIdx.x] = s;
    }
}

// ---------------------------------------------------------------- sumexp[k] = sum partial[k][:]; A row k = softmax(WA row k)
__global__ __launch_bounds__(256) void k_sumA(const float* __restrict__ partial,
                                              const float* __restrict__ WA,
                                              float* __restrict__ sumexp,
                                              float* __restrict__ A) {
    __shared__ float r[4];
    int k = blockIdx.x;
    int t = threadIdx.x;
    float s = 0.0f;
    for (int i = t; i < NBLK; i += 256) s += partial[k * PBLK + i];
#pragma unroll
    for (int off = 32; off > 0; off >>= 1) s += __shfl_xor(s, off, 64);
    if ((t & 63) == 0) r[t >> 6] = s;
    __syncthreads();
    if (t == 0) sumexp[k] = r[0] + r[1] + r[2] + r[3];
    if (t < 64) {
        float wv = WA[k * KT + t];
        float e = (t == BOS_T) ? 0.0f : __expf(wv);
        float se = e;
#pragma unroll
        for (int off = 32; off > 0; off >>= 1) se += __shfl_xor(se, off, 64);
        A[k * KT + t] = e / se + EPSF;
    }
}

// ---------------------------------------------------------------- forward scan: 1 wave = 16 sentences, phase-staged gather
__global__ __launch_bounds__(64) void k_fwd(const int* __restrict__ words,
                                            const unsigned short* __restrict__ btn_bf,
                                            const float* __restrict__ A,
                                            const float* __restrict__ sumexp,
                                            float* __restrict__ out) {
    __shared__ int shw[16 * LLEN];                                      // 8064 B
    __shared__ __attribute__((aligned(16))) unsigned short shE[2][TPH * 1024]; // 57344 B
    int lane = threadIdx.x & 63;
    int n    = lane & 15;     // sentence col (B/C side); row m (A side)
    int qA   = lane >> 4;
    int b0   = blockIdx.x * 16;

    // Stage word indices (contiguous 8064 B) -> index reads are lgkm-domain.
    {
        const uint4* src = (const uint4*)(words + (size_t)b0 * LLEN);
        uint4* dst = (uint4*)shw;
#pragma unroll
        for (int i = 0; i < 8; ++i) {
            int idx = lane + 64 * i;
            if (idx < (16 * LLEN) / 4) dst[idx] = src[idx];
        }
    }

    // A-operand frags of scaled T'^T; tag at C-position (mt, m):
    //   tagn = 32*(mt>>1) + 8*(m>>2) + 4*(mt&1) + (m&3)
    short8 Af[2][4];
#pragma unroll
    for (int mt = 0; mt < 4; ++mt) {
        int tagn = 32 * (mt >> 1) + 8 * (n >> 2) + 4 * (mt & 1) + (n & 3);
        float s = sumexp[tagn];
        float rsn = (tagn == BOS_T || tagn == EOS_T) ? 0.0f : (SCALE_F / s);
#pragma unroll
        for (int kt = 0; kt < 2; ++kt) {
            U8 f;
#pragma unroll
            for (int j = 0; j < 8; ++j)
                f.s[j] = f2bf(A[(kt * 32 + qA * 8 + j) * KT + tagn] * rsn);
            Af[kt][mt] = f.v;
        }
    }

    // beta_0 one-hot at tag 62 = B-position (kt=1, q=3, j=6)
    short8 B0, B1;
    {
        U8 z; z.u[0] = z.u[1] = z.u[2] = z.u[3] = 0;
        B0 = z.v;
        U8 o; o.u[0] = o.u[1] = o.u[2] = o.u[3] = 0;
        if (qA == 3) o.s[6] = (short)0x3F80;   // bf16(1.0)
        B1 = o.v;
    }

    // stage phase steps [t0, t0+TPH) into buffer bb: per step 2 KB,
    // half h at shorts [s*1024 + h*512 + lane*8] (= uniform base + lane*16B)
#define STAGE(bb, t0)                                                        \
    do {                                                                     \
        _Pragma("unroll")                                                    \
        for (int s_ = 0; s_ < TPH; ++s_) {                                   \
            int wd_ = shw[n * LLEN + (t0) + s_];                             \
            const unsigned short* g_ = btn_bf + (size_t)wd_ * KT + qA * 8;   \
            GLLDS(g_, &shE[bb][s_ * 1024]);                                  \
            GLLDS(g_ + 32, &shE[bb][s_ * 1024 + 512]);                       \
        }                                                                    \
    } while (0)

#define LDE(bb, ss, hh) (*(const uint4*)(&shE[bb][(ss) * 1024 + (hh) * 512] + lane * 8))

    STAGE(0, 0);
    asm volatile("s_waitcnt vmcnt(0)" ::: "memory");

    for (int p = 0; p < NPH; ++p) {
        int b = p & 1;
        if (p + 1 < NPH) STAGE((p + 1) & 1, (p + 1) * TPH);   // async, other buffer

        // compute TPH steps from buffer b (no VMEM in this loop)
        uint4 a0 = LDE(b, 0, 0), a1 = LDE(b, 0, 1);
        uint4 c0 = LDE(b, 1, 0), c1 = LDE(b, 1, 1);
#pragma unroll
        for (int s = 0; s < TPH; ++s) {
            uint4 e0 = a0, e1 = a1;
            a0 = c0; a1 = c1;
            int s2 = (s + 2 < TPH) ? s + 2 : TPH - 1;
            c0 = LDE(b, s2, 0); c1 = LDE(b, s2, 1);

            // C[mt] = Af[0][mt] x B0 + Af[1][mt] x B1
            f32x4 C[4];
#pragma unroll
            for (int mt = 0; mt < 4; ++mt) {
                f32x4 acc = {0.f, 0.f, 0.f, 0.f};
                acc = __builtin_amdgcn_mfma_f32_16x16x32_bf16(Af[0][mt], B0, acc, 0, 0, 0);
                acc = __builtin_amdgcn_mfma_f32_16x16x32_bf16(Af[1][mt], B1, acc, 0, 0, 0);
                C[mt] = acc;
            }
            // next B-frags: kt slot j <- C[2kt+(j>>2)][j&3] * e_j  (in-lane)
            U8 f0, f1;
            f0.u[0] = pk2(C[0][0] * lo16(e0.x), C[0][1] * hi16(e0.x));
            f0.u[1] = pk2(C[0][2] * lo16(e0.y), C[0][3] * hi16(e0.y));
            f0.u[2] = pk2(C[1][0] * lo16(e0.z), C[1][1] * hi16(e0.z));
            f0.u[3] = pk2(C[1][2] * lo16(e0.w), C[1][3] * hi16(e0.w));
            f1.u[0] = pk2(C[2][0] * lo16(e1.x), C[2][1] * hi16(e1.x));
            f1.u[1] = pk2(C[2][2] * lo16(e1.y), C[2][3] * hi16(e1.y));
            f1.u[2] = pk2(C[3][0] * lo16(e1.z), C[3][1] * hi16(e1.z));
            f1.u[3] = pk2(C[3][2] * lo16(e1.w), C[3][3] * hi16(e1.w));
            B0 = f0.v; B1 = f1.v;
        }
        asm volatile("s_waitcnt vmcnt(0)" ::: "memory");   // next buffer staged
    }

    // logZ = log(sum_k beta[k][n] * A[k][EOS]) - total scale
    short8 Afin[2];
#pragma unroll
    for (int kt = 0; kt < 2; ++kt) {
        U8 f;
#pragma unroll
        for (int j = 0; j < 8; ++j)
            f.s[j] = (n == 0) ? f2bf(A[(kt * 32 + qA * 8 + j) * KT + EOS_T]) : (short)0;
        Afin[kt] = f.v;
    }
    f32x4 Cf = {0.f, 0.f, 0.f, 0.f};
    Cf = __builtin_amdgcn_mfma_f32_16x16x32_bf16(Afin[0], B0, Cf, 0, 0, 0);
    Cf = __builtin_amdgcn_mfma_f32_16x16x32_bf16(Afin[1], B1, Cf, 0, 0, 0);
    if (qA == 0)
        out[b0 + n] = logf(Cf[0]) - LOG_TOTAL_SCALE;
}

extern "C" void kernel_launch(void* const* d_in, const int* in_sizes, int n_in,
                              void* d_out, int out_size, void* d_ws, size_t ws_size,
                              hipStream_t stream) {
    const int*   words  = (const int*)d_in[0];     // [8192,126]
    const float* ThetaB = (const float*)d_in[1];   // [64,128]
    const float* WA     = (const float*)d_in[2];   // [64,64]
    const float* E      = (const float*)d_in[3];   // [50000,128]
    float* out = (float*)d_out;                    // [8192]

    char* ws = (char*)d_ws;
    unsigned short* btn_bf = (unsigned short*)(ws + BTN_OFF);
    float* A       = (float*)(ws + A_OFF);
    float* sumexp  = (float*)(ws + SUM_OFF);
    float* partial = (float*)(ws + PART_OFF);

    k_emit<<<NBLK, 256, 0, stream>>>(ThetaB, E, btn_bf, partial);
    k_sumA<<<KT, 256, 0, stream>>>(partial, WA, sumexp, A);
    k_fwd<<<8192 / 16, 64, 0, stream>>>(words, btn_bf, A, sumexp, out);
}

// Round 11
// 129.799 us; speedup vs baseline: 1.0742x; 1.0742x over previous
//
#include <hip/hip_runtime.h>
#include <hip/hip_bf16.h>
#include <math.h>

// HMM forward (logZ), K=64 tags, V=50000, D=128, BATCH=8192, L=126.
// Transposed MFMA recurrence: beta_next = (T'^T x beta) .* e, with the MFMA
// C-layout -> next-step B-layout transform done by pure in-lane register
// renaming (tag relabeling absorbed into the T'^T A-operand).
// r11: producer-consumer wave specialization. r5-r10 pinned k_fwd at
// ~900 cyc/step across four inner-loop structures -> bound is per-CU
// memory-level parallelism on the random 128B-row gather (2 waves/CU).
// Now: 3 producer waves/block issue the phase's global_load_lds gathers
// (3x issue+drain parallelism), 1 consumer wave runs the LDS-only MFMA
// chain. Double-buffered 14-step phases, one __syncthreads per phase.
//
// ws layout:
//   [0, 6,400,000)        btn_bf[v][k]  bf16  raw exp(logit)
//   [6,400,000, +16384)   A[i][j]       f32   softmax(WA, col BOS=-inf)+EPS
//   [6,416,384, +256)     sumexp[k]     f32
//   [6,416,640, +200704)  partial[k][784] f32 per-block column sums

#define KT 64
#define VV 50000
#define DD 128
#define BOS_T 62
#define EOS_T 63
#define LLEN 126
#define EPSF 1e-45f
#define SCALE_F 65536.0f
#define LOG_TOTAL_SCALE (2016.0f * 0.6931471805599453f)
#define NBLK 782          // k_emit grid
#define PBLK 784          // padded partial row
#define TPH 14            // k_fwd steps per phase (126 = 9*14)
#define NPH 9

#define BTN_OFF   0
#define A_OFF     6400000
#define SUM_OFF   6416384
#define PART_OFF  6416640

typedef short short8 __attribute__((ext_vector_type(8)));
typedef float f32x4  __attribute__((ext_vector_type(4)));

union U8 { short8 v; unsigned u[4]; short s[8]; };

static __device__ inline unsigned short f2bf_u(float x) {
    __hip_bfloat16 h = __float2bfloat16(x);
    return *reinterpret_cast<unsigned short*>(&h);
}
static __device__ inline short f2bf(float x) { return (short)f2bf_u(x); }

#if __has_builtin(__builtin_amdgcn_cvt_pk_bf16_f32)
typedef __bf16 bf16x2 __attribute__((ext_vector_type(2)));
static __device__ inline unsigned pk2(float a, float b) {
    bf16x2 r = __builtin_amdgcn_cvt_pk_bf16_f32(a, b);
    return *reinterpret_cast<unsigned*>(&r);
}
#else
static __device__ inline unsigned pk2(float a, float b) {
    union { float f; unsigned u; } ua, ub;
    ua.f = a; ub.f = b;
    return ((ua.u + 0x8000u) >> 16) | ((ub.u + 0x8000u) & 0xFFFF0000u);
}
#endif
static __device__ inline float lo16(unsigned u) { union { unsigned i; float f; } c; c.i = u << 16;        return c.f; }
static __device__ inline float hi16(unsigned u) { union { unsigned i; float f; } c; c.i = u & 0xffff0000u; return c.f; }

// async global(per-lane addr) -> LDS(uniform base + lane*16B), 16 B/lane
#if __has_builtin(__builtin_amdgcn_global_load_lds)
#define GLLDS(gp, lbase)                                                        \
    __builtin_amdgcn_global_load_lds(                                           \
        (__attribute__((address_space(1))) void*)const_cast<unsigned short*>(gp),\
        (__attribute__((address_space(3))) void*)(lbase), 16, 0, 0)
#else
#define GLLDS(gp, lbase)                                                        \
    do { *(uint4*)((unsigned short*)(lbase) + (threadIdx.x & 63) * 8) =         \
             *(const uint4*)(gp); } while (0)
#endif

// ---------------------------------------------------------------- btn_bf[v][k] = bf16(exp(ThetaB[k].E[v]))  (MFMA GEMM)
__global__ __launch_bounds__(256) void k_emit(const float* __restrict__ ThetaB,
                                              const float* __restrict__ E,
                                              unsigned short* __restrict__ btn_bf,
                                              float* __restrict__ partial) {
    __shared__ float red[4][KT];
    int t    = threadIdx.x;
    int lane = t & 63;
    int w    = t >> 6;
    int n    = lane & 15;
    int q    = lane >> 4;
    int v0   = (blockIdx.x * 4 + w) * 16;

    // B-frags from E rows (cold HBM traffic — issue early): B[k=q*8+j][n=v]
    int rowE = v0 + n;
    bool valid = rowE < VV;
    rowE = valid ? rowE : VV - 1;
    float4 ex[4][2];
#pragma unroll
    for (int kt = 0; kt < 4; ++kt) {
        const float* p = E + (size_t)rowE * DD + kt * 32 + q * 8;
        ex[kt][0] = *(const float4*)p;
        ex[kt][1] = *(const float4*)(p + 4);
    }

    // A-frags from ThetaB: A[m=tag][k]: lane m=lane&15, k=q*8+j
    short8 Th[4][4];
#pragma unroll
    for (int kt = 0; kt < 4; ++kt)
#pragma unroll
        for (int mt = 0; mt < 4; ++mt) {
            const float* p = ThetaB + (mt * 16 + n) * DD + kt * 32 + q * 8;
            float4 x = *(const float4*)p;
            float4 y = *(const float4*)(p + 4);
            U8 f;
            f.u[0] = pk2(x.x, x.y); f.u[1] = pk2(x.z, x.w);
            f.u[2] = pk2(y.x, y.y); f.u[3] = pk2(y.z, y.w);
            Th[kt][mt] = f.v;
        }

    short8 Ef[4];
#pragma unroll
    for (int kt = 0; kt < 4; ++kt) {
        U8 f;
        f.u[0] = pk2(ex[kt][0].x, ex[kt][0].y); f.u[1] = pk2(ex[kt][0].z, ex[kt][0].w);
        f.u[2] = pk2(ex[kt][1].x, ex[kt][1].y); f.u[3] = pk2(ex[kt][1].z, ex[kt][1].w);
        Ef[kt] = f.v;
    }

#pragma unroll
    for (int mt = 0; mt < 4; ++mt) {
        f32x4 C = {0.f, 0.f, 0.f, 0.f};
#pragma unroll
        for (int kt = 0; kt < 4; ++kt)
            C = __builtin_amdgcn_mfma_f32_16x16x32_bf16(Th[kt][mt], Ef[kt], C, 0, 0, 0);
        // C[r]: tag = mt*16 + q*4 + r, v-col = n
        float e[4];
#pragma unroll
        for (int r = 0; r < 4; ++r) e[r] = __expf(C[r]);
        if (valid) {
            uint2 st = make_uint2(pk2(e[0], e[1]), pk2(e[2], e[3]));
            *(uint2*)(btn_bf + (size_t)rowE * KT + mt * 16 + q * 4) = st;
        }
        // column sums: reduce over the 16 v-lanes (lane bits 0-3)
#pragma unroll
        for (int r = 0; r < 4; ++r) {
            float s = valid ? e[r] : 0.0f;
            s += __shfl_xor(s, 1, 64);
            s += __shfl_xor(s, 2, 64);
            s += __shfl_xor(s, 4, 64);
            s += __shfl_xor(s, 8, 64);
            if (n == 0) red[w][mt * 16 + q * 4 + r] = s;
        }
    }
    __syncthreads();
    if (w == 0) {
        float s = red[0][lane] + red[1][lane] + red[2][lane] + red[3][lane];
        partial[lane * PBLK + blockIdx.x] = s;
    }
}

// ---------------------------------------------------------------- sumexp[k] = sum partial[k][:]; A row k = softmax(WA row k)
__global__ __launch_bounds__(256) void k_sumA(const float* __restrict__ partial,
                                              const float* __restrict__ WA,
                                              float* __restrict__ sumexp,
                                              float* __restrict__ A) {
    __shared__ float r[4];
    int k = blockIdx.x;
    int t = threadIdx.x;
    float s = 0.0f;
    for (int i = t; i < NBLK; i += 256) s += partial[k * PBLK + i];
#pragma unroll
    for (int off = 32; off > 0; off >>= 1) s += __shfl_xor(s, off, 64);
    if ((t & 63) == 0) r[t >> 6] = s;
    __syncthreads();
    if (t == 0) sumexp[k] = r[0] + r[1] + r[2] + r[3];
    if (t < 64) {
        float wv = WA[k * KT + t];
        float e = (t == BOS_T) ? 0.0f : __expf(wv);
        float se = e;
#pragma unroll
        for (int off = 32; off > 0; off >>= 1) se += __shfl_xor(se, off, 64);
        A[k * KT + t] = e / se + EPSF;
    }
}

// ---------------------------------------------------------------- forward scan: 4 waves/block, 3 producers + 1 consumer
__global__ __launch_bounds__(256) void k_fwd(const int* __restrict__ words,
                                             const unsigned short* __restrict__ btn_bf,
                                             const float* __restrict__ A,
                                             const float* __restrict__ sumexp,
                                             float* __restrict__ out) {
    __shared__ int shw[16 * LLEN];                                      // 8064 B
    __shared__ __attribute__((aligned(16))) unsigned short shE[2][TPH * 1024]; // 57344 B
    int lane = threadIdx.x & 63;
    int w    = threadIdx.x >> 6;   // waves 0-2: producers, wave 3: consumer
    int n    = lane & 15;          // sentence col (B/C side); row m (A side)
    int qA   = lane >> 4;
    int b0   = blockIdx.x * 16;

    // Stage word indices (contiguous 8064 B) cooperatively.
    {
        const uint4* src = (const uint4*)(words + (size_t)b0 * LLEN);
        uint4* dst = (uint4*)shw;
        for (int idx = threadIdx.x; idx < (16 * LLEN) / 4; idx += 256)
            dst[idx] = src[idx];
    }

    // Consumer-only state
    short8 Af[2][4];
    short8 B0, B1;
    if (w == 3) {
        // A-operand frags of scaled T'^T; tag at C-position (mt, m):
        //   tagn = 32*(mt>>1) + 8*(m>>2) + 4*(mt&1) + (m&3)
#pragma unroll
        for (int mt = 0; mt < 4; ++mt) {
            int tagn = 32 * (mt >> 1) + 8 * (n >> 2) + 4 * (mt & 1) + (n & 3);
            float s = sumexp[tagn];
            float rsn = (tagn == BOS_T || tagn == EOS_T) ? 0.0f : (SCALE_F / s);
#pragma unroll
            for (int kt = 0; kt < 2; ++kt) {
                U8 f;
#pragma unroll
                for (int j = 0; j < 8; ++j)
                    f.s[j] = f2bf(A[(kt * 32 + qA * 8 + j) * KT + tagn] * rsn);
                Af[kt][mt] = f.v;
            }
        }
        // beta_0 one-hot at tag 62 = B-position (kt=1, q=3, j=6)
        U8 z; z.u[0] = z.u[1] = z.u[2] = z.u[3] = 0;
        B0 = z.v;
        U8 o; o.u[0] = o.u[1] = o.u[2] = o.u[3] = 0;
        if (qA == 3) o.s[6] = (short)0x3F80;   // bf16(1.0)
        B1 = o.v;
    }
    __syncthreads();   // shw staged

    // producer staging of phase p into buffer bb: wave w takes steps w, w+3, ...
#define PSTAGE(bb, p_)                                                        \
    do {                                                                      \
        for (int s_ = w; s_ < TPH; s_ += 3) {                                 \
            int wd_ = shw[n * LLEN + (p_) * TPH + s_];                        \
            const unsigned short* g_ = btn_bf + (size_t)wd_ * KT + qA * 8;    \
            GLLDS(g_, &shE[bb][s_ * 1024]);                                   \
            GLLDS(g_ + 32, &shE[bb][s_ * 1024 + 512]);                        \
        }                                                                     \
        asm volatile("s_waitcnt vmcnt(0)" ::: "memory");                      \
    } while (0)

#define LDE(bb, ss, hh) (*(const uint4*)(&shE[bb][(ss) * 1024 + (hh) * 512] + lane * 8))

    if (w < 3) PSTAGE(0, 0);
    __syncthreads();   // phase 0 ready

    for (int p = 0; p < NPH; ++p) {
        int b = p & 1;
        if (w < 3) {
            if (p + 1 < NPH) PSTAGE((p + 1) & 1, p + 1);
        } else {
            // consumer: TPH steps from buffer b, no VMEM
            uint4 a0 = LDE(b, 0, 0), a1 = LDE(b, 0, 1);
            uint4 c0 = LDE(b, 1, 0), c1 = LDE(b, 1, 1);
#pragma unroll
            for (int s = 0; s < TPH; ++s) {
                uint4 e0 = a0, e1 = a1;
                a0 = c0; a1 = c1;
                int s2 = (s + 2 < TPH) ? s + 2 : TPH - 1;
                c0 = LDE(b, s2, 0); c1 = LDE(b, s2, 1);

                // C[mt] = Af[0][mt] x B0 + Af[1][mt] x B1
                f32x4 C[4];
#pragma unroll
                for (int mt = 0; mt < 4; ++mt) {
                    f32x4 acc = {0.f, 0.f, 0.f, 0.f};
                    acc = __builtin_amdgcn_mfma_f32_16x16x32_bf16(Af[0][mt], B0, acc, 0, 0, 0);
                    acc = __builtin_amdgcn_mfma_f32_16x16x32_bf16(Af[1][mt], B1, acc, 0, 0, 0);
                    C[mt] = acc;
                }
                // next B-frags: kt slot j <- C[2kt+(j>>2)][j&3] * e_j  (in-lane)
                U8 f0, f1;
                f0.u[0] = pk2(C[0][0] * lo16(e0.x), C[0][1] * hi16(e0.x));
                f0.u[1] = pk2(C[0][2] * lo16(e0.y), C[0][3] * hi16(e0.y));
                f0.u[2] = pk2(C[1][0] * lo16(e0.z), C[1][1] * hi16(e0.z));
                f0.u[3] = pk2(C[1][2] * lo16(e0.w), C[1][3] * hi16(e0.w));
                f1.u[0] = pk2(C[2][0] * lo16(e1.x), C[2][1] * hi16(e1.x));
                f1.u[1] = pk2(C[2][2] * lo16(e1.y), C[2][3] * hi16(e1.y));
                f1.u[2] = pk2(C[3][0] * lo16(e1.z), C[3][1] * hi16(e1.z));
                f1.u[3] = pk2(C[3][2] * lo16(e1.w), C[3][3] * hi16(e1.w));
                B0 = f0.v; B1 = f1.v;
            }
        }
        __syncthreads();   // producers drained next phase; consumer done with b
    }

    // logZ = log(sum_k beta[k][n] * A[k][EOS]) - total scale
    if (w == 3) {
        short8 Afin[2];
#pragma unroll
        for (int kt = 0; kt < 2; ++kt) {
            U8 f;
#pragma unroll
            for (int j = 0; j < 8; ++j)
                f.s[j] = (n == 0) ? f2bf(A[(kt * 32 + qA * 8 + j) * KT + EOS_T]) : (short)0;
            Afin[kt] = f.v;
        }
        f32x4 Cf = {0.f, 0.f, 0.f, 0.f};
        Cf = __builtin_amdgcn_mfma_f32_16x16x32_bf16(Afin[0], B0, Cf, 0, 0, 0);
        Cf = __builtin_amdgcn_mfma_f32_16x16x32_bf16(Afin[1], B1, Cf, 0, 0, 0);
        if (qA == 0)
            out[b0 + n] = logf(Cf[0]) - LOG_TOTAL_SCALE;
    }
}

extern "C" void kernel_launch(void* const* d_in, const int* in_sizes, int n_in,
                              void* d_out, int out_size, void* d_ws, size_t ws_size,
                              hipStream_t stream) {
    const int*   words  = (const int*)d_in[0];     // [8192,126]
    const float* ThetaB = (const float*)d_in[1];   // [64,128]
    const float* WA     = (const float*)d_in[2];   // [64,64]
    const float* E      = (const float*)d_in[3];   // [50000,128]
    float* out = (float*)d_out;                    // [8192]

    char* ws = (char*)d_ws;
    unsigned short* btn_bf = (unsigned short*)(ws + BTN_OFF);
    float* A       = (float*)(ws + A_OFF);
    float* sumexp  = (float*)(ws + SUM_OFF);
    float* partial = (float*)(ws + PART_OFF);

    k_emit<<<NBLK, 256, 0, stream>>>(ThetaB, E, btn_bf, partial);
    k_sumA<<<KT, 256, 0, stream>>>(partial, WA, sumexp, A);
    k_fwd<<<8192 / 16, 256, 0, stream>>>(words, btn_bf, A, sumexp, out);
}

// Round 12
// 127.677 us; speedup vs baseline: 1.0920x; 1.0166x over previous
//
#include <hip/hip_runtime.h>
#include <hip/hip_bf16.h>
#include <math.h>

// HMM forward (logZ), K=64 tags, V=50000, D=128, BATCH=8192, L=126.
// Transposed MFMA recurrence: beta_next = (T'^T x beta) .* e; the MFMA
// C-layout -> next-step B-layout transform is pure in-lane register renaming
// (tag relabeling absorbed into the T'^T A-operand). Producer-consumer wave
// specialization (r11). r12: emission table stored as fp8 e4m3, row layout
// permuted so each (sentence, qA) lane's 16 tag-values are one contiguous
// 16B chunk: table = 3.2 MB -> fits the 4 MB per-XCD L2 (r11's producers ate
// L3 latency on a 6.4 MB bf16 table); 1 global_load_lds per step (was 2);
// phase buffers halve -> TPH=21, NPH=6 (fewer barriers). beta stays bf16.
//
// fp8 row layout: tag k = 32*h + 8*qA + j  ->  byte 16*qA + 8*h + j.
//
// ws layout:
//   [0, 3,200,000)        btn8[v][64]   fp8e4m3  raw exp(logit), permuted order
//   [3,200,000, +16384)   A[i][j]       f32      softmax(WA, col BOS=-inf)+EPS
//   [3,216,384, +256)     sumexp[k]     f32
//   [3,216,640, +200704)  partial[k][784] f32    per-block column sums

#define KT 64
#define VV 50000
#define DD 128
#define BOS_T 62
#define EOS_T 63
#define LLEN 126
#define EPSF 1e-45f
#define SCALE_F 65536.0f
#define LOG_TOTAL_SCALE (2016.0f * 0.6931471805599453f)
#define NBLK 782          // k_emit grid
#define PBLK 784          // padded partial row
#define TPH 21            // k_fwd steps per phase (126 = 6*21)
#define NPH 6

#define BTN_OFF   0
#define A_OFF     3200000
#define SUM_OFF   3216384
#define PART_OFF  3216640

typedef short short8 __attribute__((ext_vector_type(8)));
typedef float f32x4  __attribute__((ext_vector_type(4)));
typedef float f32x2  __attribute__((ext_vector_type(2)));

union U8 { short8 v; unsigned u[4]; short s[8]; };

static __device__ inline unsigned short f2bf_u(float x) {
    __hip_bfloat16 h = __float2bfloat16(x);
    return *reinterpret_cast<unsigned short*>(&h);
}
static __device__ inline short f2bf(float x) { return (short)f2bf_u(x); }

#if __has_builtin(__builtin_amdgcn_cvt_pk_bf16_f32)
typedef __bf16 bf16x2 __attribute__((ext_vector_type(2)));
static __device__ inline unsigned pk2(float a, float b) {
    bf16x2 r = __builtin_amdgcn_cvt_pk_bf16_f32(a, b);
    return *reinterpret_cast<unsigned*>(&r);
}
#else
static __device__ inline unsigned pk2(float a, float b) {
    union { float f; unsigned u; } ua, ub;
    ua.f = a; ub.f = b;
    return ((ua.u + 0x8000u) >> 16) | ((ub.u + 0x8000u) & 0xFFFF0000u);
}
#endif
static __device__ inline float lo16(unsigned u) { union { unsigned i; float f; } c; c.i = u << 16;        return c.f; }
static __device__ inline float hi16(unsigned u) { union { unsigned i; float f; } c; c.i = u & 0xffff0000u; return c.f; }

// ---- fp8 e4m3fn pack/unpack (values here are positive normals in [0.7,1.5])
#if __has_builtin(__builtin_amdgcn_cvt_pk_fp8_f32)
static __device__ inline unsigned pk4f8(float a, float b, float c, float d) {
    int v = __builtin_amdgcn_cvt_pk_fp8_f32(a, b, 0, false);
    v = __builtin_amdgcn_cvt_pk_fp8_f32(c, d, v, true);
    return (unsigned)v;
}
#else
static __device__ inline unsigned enc1f8(float x) {
    union { float f; unsigned u; } c; c.f = x;
    unsigned u = c.u & 0x7FFFFFFFu;
    unsigned r = u + 0x7FFFFu + ((u >> 20) & 1u);   // RNE to 3 mantissa bits
    return ((r >> 20) - (120u << 3)) & 0x7Fu;       // rebias 127->7
}
static __device__ inline unsigned pk4f8(float a, float b, float c, float d) {
    return enc1f8(a) | (enc1f8(b) << 8) | (enc1f8(c) << 16) | (enc1f8(d) << 24);
}
#endif

#if __has_builtin(__builtin_amdgcn_cvt_pk_f32_fp8)
static __device__ inline f32x2 dec2lo(unsigned w) { return __builtin_amdgcn_cvt_pk_f32_fp8((int)w, false); }
static __device__ inline f32x2 dec2hi(unsigned w) { return __builtin_amdgcn_cvt_pk_f32_fp8((int)w, true); }
#else
static __device__ inline float dec1f8(unsigned b) {
    union { unsigned u; float f; } c;
    c.u = ((b & 0x80u) << 24) | (((b & 0x7Fu) << 20) + (120u << 23));
    return c.f;
}
static __device__ inline f32x2 dec2lo(unsigned w) { f32x2 r; r.x = dec1f8(w & 0xFF); r.y = dec1f8((w >> 8) & 0xFF); return r; }
static __device__ inline f32x2 dec2hi(unsigned w) { f32x2 r; r.x = dec1f8((w >> 16) & 0xFF); r.y = dec1f8(w >> 24); return r; }
#endif

// async global(per-lane addr) -> LDS(uniform base + lane*16B), 16 B/lane
#if __has_builtin(__builtin_amdgcn_global_load_lds)
#define GLLDS(gp, lbase)                                                        \
    __builtin_amdgcn_global_load_lds(                                           \
        (__attribute__((address_space(1))) void*)const_cast<unsigned char*>(gp),\
        (__attribute__((address_space(3))) void*)(lbase), 16, 0, 0)
#else
#define GLLDS(gp, lbase)                                                        \
    do { *(uint4*)((unsigned char*)(lbase) + (threadIdx.x & 63) * 16) =         \
             *(const uint4*)(gp); } while (0)
#endif

// ---------------------------------------------------------------- btn8[v][pos(k)] = fp8(exp(ThetaB[k].E[v]))  (MFMA GEMM)
__global__ __launch_bounds__(256) void k_emit(const float* __restrict__ ThetaB,
                                              const float* __restrict__ E,
                                              unsigned char* __restrict__ btn8,
                                              float* __restrict__ partial) {
    __shared__ float red[4][KT];
    int t    = threadIdx.x;
    int lane = t & 63;
    int w    = t >> 6;
    int n    = lane & 15;
    int q    = lane >> 4;
    int v0   = (blockIdx.x * 4 + w) * 16;

    // B-frags from E rows (cold HBM traffic — issue early): B[k=q*8+j][n=v]
    int rowE = v0 + n;
    bool valid = rowE < VV;
    rowE = valid ? rowE : VV - 1;
    float4 ex[4][2];
#pragma unroll
    for (int kt = 0; kt < 4; ++kt) {
        const float* p = E + (size_t)rowE * DD + kt * 32 + q * 8;
        ex[kt][0] = *(const float4*)p;
        ex[kt][1] = *(const float4*)(p + 4);
    }

    // A-frags from ThetaB: A[m=tag][k]: lane m=lane&15, k=q*8+j
    short8 Th[4][4];
#pragma unroll
    for (int kt = 0; kt < 4; ++kt)
#pragma unroll
        for (int mt = 0; mt < 4; ++mt) {
            const float* p = ThetaB + (mt * 16 + n) * DD + kt * 32 + q * 8;
            float4 x = *(const float4*)p;
            float4 y = *(const float4*)(p + 4);
            U8 f;
            f.u[0] = pk2(x.x, x.y); f.u[1] = pk2(x.z, x.w);
            f.u[2] = pk2(y.x, y.y); f.u[3] = pk2(y.z, y.w);
            Th[kt][mt] = f.v;
        }

    short8 Ef[4];
#pragma unroll
    for (int kt = 0; kt < 4; ++kt) {
        U8 f;
        f.u[0] = pk2(ex[kt][0].x, ex[kt][0].y); f.u[1] = pk2(ex[kt][0].z, ex[kt][0].w);
        f.u[2] = pk2(ex[kt][1].x, ex[kt][1].y); f.u[3] = pk2(ex[kt][1].z, ex[kt][1].w);
        Ef[kt] = f.v;
    }

#pragma unroll
    for (int mt = 0; mt < 4; ++mt) {
        f32x4 C = {0.f, 0.f, 0.f, 0.f};
#pragma unroll
        for (int kt = 0; kt < 4; ++kt)
            C = __builtin_amdgcn_mfma_f32_16x16x32_bf16(Th[kt][mt], Ef[kt], C, 0, 0, 0);
        // C[r]: tag t = mt*16 + q*4 + r, v-col = n
        float e[4];
#pragma unroll
        for (int r = 0; r < 4; ++r) e[r] = __expf(C[r]);
        if (valid) {
            // permuted byte position of tag t = 32h + 8qA + j: 16*qA + 8*h + j
            // for t = mt*16 + q*4 + r: qA=(2mt+(q>>1))&3, h=mt>>1, j=(q&1)*4+r
            int pos = 16 * ((2 * mt + (q >> 1)) & 3) + 8 * (mt >> 1) + (q & 1) * 4;
            *(unsigned*)(btn8 + (size_t)rowE * KT + pos) = pk4f8(e[0], e[1], e[2], e[3]);
        }
        // column sums: reduce over the 16 v-lanes (lane bits 0-3)
#pragma unroll
        for (int r = 0; r < 4; ++r) {
            float s = valid ? e[r] : 0.0f;
            s += __shfl_xor(s, 1, 64);
            s += __shfl_xor(s, 2, 64);
            s += __shfl_xor(s, 4, 64);
            s += __shfl_xor(s, 8, 64);
            if (n == 0) red[w][mt * 16 + q * 4 + r] = s;
        }
    }
    __syncthreads();
    if (w == 0) {
        float s = red[0][lane] + red[1][lane] + red[2][lane] + red[3][lane];
        partial[lane * PBLK + blockIdx.x] = s;
    }
}

// ---------------------------------------------------------------- sumexp[k] = sum partial[k][:]; A row k = softmax(WA row k)
__global__ __launch_bounds__(256) void k_sumA(const float* __restrict__ partial,
                                              const float* __restrict__ WA,
                                              float* __restrict__ sumexp,
                                              float* __restrict__ A) {
    __shared__ float r[4];
    int k = blockIdx.x;
    int t = threadIdx.x;
    float s = 0.0f;
    for (int i = t; i < NBLK; i += 256) s += partial[k * PBLK + i];
#pragma unroll
    for (int off = 32; off > 0; off >>= 1) s += __shfl_xor(s, off, 64);
    if ((t & 63) == 0) r[t >> 6] = s;
    __syncthreads();
    if (t == 0) sumexp[k] = r[0] + r[1] + r[2] + r[3];
    if (t < 64) {
        float wv = WA[k * KT + t];
        float e = (t == BOS_T) ? 0.0f : __expf(wv);
        float se = e;
#pragma unroll
        for (int off = 32; off > 0; off >>= 1) se += __shfl_xor(se, off, 64);
        A[k * KT + t] = e / se + EPSF;
    }
}

// ---------------------------------------------------------------- forward scan: 4 waves/block, 3 producers + 1 consumer
__global__ __launch_bounds__(256) void k_fwd(const int* __restrict__ words,
                                             const unsigned char* __restrict__ btn8,
                                             const float* __restrict__ A,
                                             const float* __restrict__ sumexp,
                                             float* __restrict__ out) {
    __shared__ int shw[16 * LLEN];                                            // 8064 B
    __shared__ __attribute__((aligned(16))) unsigned char shE[2][TPH * 1024]; // 43008 B
    int lane = threadIdx.x & 63;
    int w    = threadIdx.x >> 6;   // waves 0-2: producers, wave 3: consumer
    int n    = lane & 15;          // sentence col (B/C side); row m (A side)
    int qA   = lane >> 4;
    int b0   = blockIdx.x * 16;

    // Stage word indices (contiguous 8064 B) cooperatively.
    {
        const uint4* src = (const uint4*)(words + (size_t)b0 * LLEN);
        uint4* dst = (uint4*)shw;
        for (int idx = threadIdx.x; idx < (16 * LLEN) / 4; idx += 256)
            dst[idx] = src[idx];
    }

    // Consumer-only state
    short8 Af[2][4];
    short8 B0, B1;
    if (w == 3) {
        // A-operand frags of scaled T'^T; tag at C-position (mt, m):
        //   tagn = 32*(mt>>1) + 8*(m>>2) + 4*(mt&1) + (m&3)
#pragma unroll
        for (int mt = 0; mt < 4; ++mt) {
            int tagn = 32 * (mt >> 1) + 8 * (n >> 2) + 4 * (mt & 1) + (n & 3);
            float s = sumexp[tagn];
            float rsn = (tagn == BOS_T || tagn == EOS_T) ? 0.0f : (SCALE_F / s);
#pragma unroll
            for (int kt = 0; kt < 2; ++kt) {
                U8 f;
#pragma unroll
                for (int j = 0; j < 8; ++j)
                    f.s[j] = f2bf(A[(kt * 32 + qA * 8 + j) * KT + tagn] * rsn);
                Af[kt][mt] = f.v;
            }
        }
        // beta_0 one-hot at tag 62 = B-position (kt=1, q=3, j=6)
        U8 z; z.u[0] = z.u[1] = z.u[2] = z.u[3] = 0;
        B0 = z.v;
        U8 o; o.u[0] = o.u[1] = o.u[2] = o.u[3] = 0;
        if (qA == 3) o.s[6] = (short)0x3F80;   // bf16(1.0)
        B1 = o.v;
    }
    __syncthreads();   // shw staged

    // producer staging of phase p_ into buffer bb: wave w takes steps w, w+3, ...
    // one GLLDS per step: 64 lanes x 16B = 16 sentences' permuted fp8 rows
#define PSTAGE(bb, p_)                                                        \
    do {                                                                      \
        for (int s_ = w; s_ < TPH; s_ += 3) {                                 \
            int wd_ = shw[n * LLEN + (p_) * TPH + s_];                        \
            const unsigned char* g_ = btn8 + (size_t)wd_ * KT + qA * 16;      \
            GLLDS(g_, &shE[bb][s_ * 1024]);                                   \
        }                                                                     \
        asm volatile("s_waitcnt vmcnt(0)" ::: "memory");                      \
    } while (0)

#define LDE(bb, ss) (*(const uint4*)(&shE[bb][(ss) * 1024] + lane * 16))

    if (w < 3) PSTAGE(0, 0);
    __syncthreads();   // phase 0 ready

    for (int p = 0; p < NPH; ++p) {
        int b = p & 1;
        if (w < 3) {
            if (p + 1 < NPH) PSTAGE((p + 1) & 1, p + 1);
        } else {
            // consumer: TPH steps from buffer b, no VMEM
            uint4 r0 = LDE(b, 0);
            uint4 r1 = LDE(b, 1);
#pragma unroll
            for (int s = 0; s < TPH; ++s) {
                uint4 rc = r0;
                r0 = r1;
                int s2 = (s + 2 < TPH) ? s + 2 : TPH - 1;
                r1 = LDE(b, s2);

                // decode 16 fp8 (prefetched 2 steps ago -> off the chain)
                f32x2 d0 = dec2lo(rc.x), d1 = dec2hi(rc.x);
                f32x2 d2 = dec2lo(rc.y), d3 = dec2hi(rc.y);
                f32x2 d4 = dec2lo(rc.z), d5 = dec2hi(rc.z);
                f32x2 d6 = dec2lo(rc.w), d7 = dec2hi(rc.w);

                // C[mt] = Af[0][mt] x B0 + Af[1][mt] x B1
                f32x4 C[4];
#pragma unroll
                for (int mt = 0; mt < 4; ++mt) {
                    f32x4 acc = {0.f, 0.f, 0.f, 0.f};
                    acc = __builtin_amdgcn_mfma_f32_16x16x32_bf16(Af[0][mt], B0, acc, 0, 0, 0);
                    acc = __builtin_amdgcn_mfma_f32_16x16x32_bf16(Af[1][mt], B1, acc, 0, 0, 0);
                    C[mt] = acc;
                }
                // next B-frags: kt slot j <- C[2kt+(j>>2)][j&3] * e_j  (in-lane)
                U8 f0, f1;
                f0.u[0] = pk2(C[0][0] * d0.x, C[0][1] * d0.y);
                f0.u[1] = pk2(C[0][2] * d1.x, C[0][3] * d1.y);
                f0.u[2] = pk2(C[1][0] * d2.x, C[1][1] * d2.y);
                f0.u[3] = pk2(C[1][2] * d3.x, C[1][3] * d3.y);
                f1.u[0] = pk2(C[2][0] * d4.x, C[2][1] * d4.y);
                f1.u[1] = pk2(C[2][2] * d5.x, C[2][3] * d5.y);
                f1.u[2] = pk2(C[3][0] * d6.x, C[3][1] * d6.y);
                f1.u[3] = pk2(C[3][2] * d7.x, C[3][3] * d7.y);
                B0 = f0.v; B1 = f1.v;
            }
        }
        __syncthreads();   // producers drained next phase; consumer done with b
    }

    // logZ = log(sum_k beta[k][n] * A[k][EOS]) - total scale
    if (w == 3) {
        short8 Afin[2];
#pragma unroll
        for (int kt = 0; kt < 2; ++kt) {
            U8 f;
#pragma unroll
            for (int j = 0; j < 8; ++j)
                f.s[j] = (n == 0) ? f2bf(A[(kt * 32 + qA * 8 + j) * KT + EOS_T]) : (short)0;
            Afin[kt] = f.v;
        }
        f32x4 Cf = {0.f, 0.f, 0.f, 0.f};
        Cf = __builtin_amdgcn_mfma_f32_16x16x32_bf16(Afin[0], B0, Cf, 0, 0, 0);
        Cf = __builtin_amdgcn_mfma_f32_16x16x32_bf16(Afin[1], B1, Cf, 0, 0, 0);
        if (qA == 0)
            out[b0 + n] = logf(Cf[0]) - LOG_TOTAL_SCALE;
    }
}

extern "C" void kernel_launch(void* const* d_in, const int* in_sizes, int n_in,
                              void* d_out, int out_size, void* d_ws, size_t ws_size,
                              hipStream_t stream) {
    const int*   words  = (const int*)d_in[0];     // [8192,126]
    const float* ThetaB = (const float*)d_in[1];   // [64,128]
    const float* WA     = (const float*)d_in[2];   // [64,64]
    const float* E      = (const float*)d_in[3];   // [50000,128]
    float* out = (float*)d_out;                    // [8192]

    char* ws = (char*)d_ws;
    unsigned char* btn8 = (unsigned char*)(ws + BTN_OFF);
    float* A       = (float*)(ws + A_OFF);
    float* sumexp  = (float*)(ws + SUM_OFF);
    float* partial = (float*)(ws + PART_OFF);

    k_emit<<<NBLK, 256, 0, stream>>>(ThetaB, E, btn8, partial);
    k_sumA<<<KT, 256, 0, stream>>>(partial, WA, sumexp, A);
    k_fwd<<<8192 / 16, 256, 0, stream>>>(words, btn8, A, sumexp, out);
}